// Round 22
// baseline (55.819 us; speedup 1.0000x reference)
//
#include <hip/hip_runtime.h>

typedef short bf16x8 __attribute__((ext_vector_type(8)));
typedef float f32x16 __attribute__((ext_vector_type(16)));

#define CIN 64
#define OC 18
#define NB 4
#define H 256
#define W 256
#define HW (H * W)
#define OH 128
#define OW 128
#define EPS 1e-5f

#define TSX 16          // conv tile cols
#define TSY 8           // conv tile rows
#define NTILE 4         // tiles per conv block
#define NWB 512         // number of conv blocks
#define ASLOTS 1536     // A halo: 1440 uint4 padded

__device__ __forceinline__ int refl(int i, int n) {
    if (i < 0) i = -i;
    if (i >= n) i = 2 * n - 2 - i;
    return i;
}

__device__ __forceinline__ unsigned pack_bf16(float a, float b) {
    __bf16 lo = (__bf16)a, hi = (__bf16)b;
    return (unsigned)__builtin_bit_cast(unsigned short, lo) |
           ((unsigned)__builtin_bit_cast(unsigned short, hi) << 16);
}

__device__ __forceinline__ void gload_lds16(const uint4* g, uint4* l) {
    __builtin_amdgcn_global_load_lds(
        (const __attribute__((address_space(1))) void*)(g),
        (__attribute__((address_space(3))) void*)(l), 16, 0, 0);
}

// ---------------------------------------------------------------------------
// NCHW fp32 -> NHWC bf16 transpose (+ fused weight repack on blockIdx.y==NB).
// ---------------------------------------------------------------------------
__global__ __launch_bounds__(256) void nhwc_kernel(
        const float* __restrict__ x, uint4* __restrict__ xt,
        const float* __restrict__ wgt, uint4* __restrict__ wB)
{
    if (blockIdx.y == NB) {
        if (blockIdx.x < 9) {
            int idx = blockIdx.x * 256 + threadIdx.x;   // s*64 + l
            int s = idx >> 6, l = idx & 63;
            int tap = s >> 2, ci0 = (s & 3) * 16;
            int oc = l & 31, kg = l >> 5;
            unsigned r[4];
#pragma unroll
            for (int jp = 0; jp < 4; jp++) {
                float v0 = 0.f, v1 = 0.f;
                int ci = ci0 + kg * 8 + jp * 2;
                if (oc < OC) {
                    v0 = wgt[(oc * CIN + ci) * 9 + tap];
                    v1 = wgt[(oc * CIN + ci + 1) * 9 + tap];
                }
                r[jp] = pack_bf16(v0, v1);
            }
            wB[idx] = make_uint4(r[0], r[1], r[2], r[3]);
        }
        return;
    }

    __shared__ uint4 bufq[2048];          // 32 KB
    unsigned* buf = (unsigned*)bufq;

    const int h = blockIdx.x, n = blockIdx.y;
    const int t = threadIdx.x;
    const int tpx = t & 63;
    const int cg = t >> 6;
    const int px0 = tpx * 4;
    const unsigned swz = ((unsigned)tpx & 7u) << 2;

    const float* xrow = x + ((size_t)n * CIN * H + h) * W;

#pragma unroll
    for (int ii = 0; ii < 4; ii++) {
        const int cq = cg * 4 + ii;
        const float4 A0 = *(const float4*)(xrow + (size_t)(4 * cq + 0) * HW + px0);
        const float4 A1 = *(const float4*)(xrow + (size_t)(4 * cq + 1) * HW + px0);
        const float4 A2 = *(const float4*)(xrow + (size_t)(4 * cq + 2) * HW + px0);
        const float4 A3 = *(const float4*)(xrow + (size_t)(4 * cq + 3) * HW + px0);
        const float a0[4] = {A0.x, A0.y, A0.z, A0.w};
        const float a1[4] = {A1.x, A1.y, A1.z, A1.w};
        const float a2[4] = {A2.x, A2.y, A2.z, A2.w};
        const float a3[4] = {A3.x, A3.y, A3.z, A3.w};
#pragma unroll
        for (int i = 0; i < 4; i++) {
            unsigned lo = pack_bf16(a0[i], a1[i]);
            unsigned hi = pack_bf16(a2[i], a3[i]);
            unsigned widx = (unsigned)(px0 + i) * 32u + ((unsigned)(2 * cq) ^ swz);
            *(uint2*)&buf[widx] = make_uint2(lo, hi);
        }
    }
    __syncthreads();

    const size_t rowbase = ((size_t)(n * H + h)) * W * 8;
#pragma unroll
    for (int i = 0; i < 8; i++) {
        int flat = i * 256 + t;
        int px = flat >> 3, j = flat & 7;
        unsigned sw = (((unsigned)px >> 2) & 7u) << 2;
        uint4 v = *(const uint4*)&buf[(unsigned)px * 32u + (((unsigned)(4 * j)) ^ sw)];
        xt[rowbase + flat] = v;
    }
}

// ---------------------------------------------------------------------------
// Kernel A: persistent-tile implicit-GEMM bf16 MFMA conv (r21, unchanged).
// A staged via ASYNC global_load_lds width-16 (src octet swizzle c^=(px&7));
// B in 36 NAMED uint4 registers. ONE barrier per tile.
// BN partials to part[36][NWB].
// ---------------------------------------------------------------------------
__global__ __launch_bounds__(256, 2) void conv_kernel(
        const uint4* __restrict__ xt, const uint4* __restrict__ wB,
        float* __restrict__ sigma_s, float* __restrict__ part)
{
    __shared__ uint4 aldsq[2][ASLOTS];     // 2 x 24,576 B
    __shared__ float sred[2 * OC];

    const int tid = threadIdx.x;
    const int lane = tid & 63;

    const int b = blockIdx.x;
    const int cls = b & 7;
    const int L = b >> 3;
    const int n = cls >> 1;
    const int hhalf = cls & 1;
    const int ht = L >> 2;
    const int wq = L & 3;
    const int h0 = (hhalf * 16 + ht) * TSY;
    const int w0 = wq * (NTILE * TSX);

    if (tid < 2 * OC) sred[tid] = 0.f;

    int gbase[6], apx[6];
#pragma unroll
    for (int i = 0; i < 6; i++) {
        int e = tid + i * 256;
        int row = e / 144;
        int rem = e - row * 144;
        int px  = rem >> 3;
        int cs  = rem & 7;
        int csrc = cs ^ (px & 7);
        int gh  = refl(h0 + row - 1, H);
        gbase[i] = (n * H + gh) * W * 8 + csrc;
        apx[i]  = px;
    }

    // issue A tile 0 (async)
#pragma unroll
    for (int i = 0; i < 6; i++) {
        int gw = refl(w0 + apx[i] - 1, W);
        gload_lds16(xt + (size_t)gbase[i] + (size_t)gw * 8,
                    &aldsq[0][tid + i * 256]);
    }

    // B fragments -> 36 NAMED registers (wB zero-padded for oc>=18)
    const uint4* wL = wB + lane;
    uint4 b00 = wL[ 0*64], b01 = wL[ 1*64], b02 = wL[ 2*64], b03 = wL[ 3*64];
    uint4 b04 = wL[ 4*64], b05 = wL[ 5*64], b06 = wL[ 6*64], b07 = wL[ 7*64];
    uint4 b08 = wL[ 8*64], b09 = wL[ 9*64], b10 = wL[10*64], b11 = wL[11*64];
    uint4 b12 = wL[12*64], b13 = wL[13*64], b14 = wL[14*64], b15 = wL[15*64];
    uint4 b16 = wL[16*64], b17 = wL[17*64], b18 = wL[18*64], b19 = wL[19*64];
    uint4 b20 = wL[20*64], b21 = wL[21*64], b22 = wL[22*64], b23 = wL[23*64];
    uint4 b24 = wL[24*64], b25 = wL[25*64], b26 = wL[26*64], b27 = wL[27*64];
    uint4 b28 = wL[28*64], b29 = wL[29*64], b30 = wL[30*64], b31 = wL[31*64];
    uint4 b32 = wL[32*64], b33 = wL[33*64], b34 = wL[34*64], b35 = wL[35*64];

    __syncthreads();

    const int wv = tid >> 6;
    const int m = lane & 31;
    const int kg = lane >> 5;
    const int pr = m >> 4, pc = m & 15;
    const int r0 = 2 * wv + pr;

    float s_acc = 0.f, ss_acc = 0.f;
    const int oy = (h0 >> 1) + wv;
    const size_t pb_n = (size_t)n * OC;

#define CSTEP(G, Q, BV)                                                        \
    {                                                                          \
        const int rp  = (r0 + (G / 3)) * 144 + (pc + (G % 3)) * 8;             \
        const int swk = (pc + (G % 3)) & 7;                                    \
        uint4 af = aq[rp + ((kg + 2 * (Q)) ^ swk)];                            \
        acc = __builtin_amdgcn_mfma_f32_32x32x16_bf16(                         \
                __builtin_bit_cast(bf16x8, af),                                \
                __builtin_bit_cast(bf16x8, BV), acc, 0, 0, 0);                 \
    }

#pragma unroll 1
    for (int t = 0; t < NTILE; t++) {
        if (t + 1 < NTILE) {
            const int w0n = w0 + (t + 1) * TSX;
            uint4* dst = &aldsq[(t + 1) & 1][0];
#pragma unroll
            for (int i = 0; i < 6; i++) {
                int gw = refl(w0n + apx[i] - 1, W);
                gload_lds16(xt + (size_t)gbase[i] + (size_t)gw * 8,
                            dst + tid + i * 256);
            }
        }

        const uint4* aq = &aldsq[t & 1][0];
        f32x16 acc = {};
        CSTEP(0, 0, b00) CSTEP(0, 1, b01) CSTEP(0, 2, b02) CSTEP(0, 3, b03)
        CSTEP(1, 0, b04) CSTEP(1, 1, b05) CSTEP(1, 2, b06) CSTEP(1, 3, b07)
        CSTEP(2, 0, b08) CSTEP(2, 1, b09) CSTEP(2, 2, b10) CSTEP(2, 3, b11)
        CSTEP(3, 0, b12) CSTEP(3, 1, b13) CSTEP(3, 2, b14) CSTEP(3, 3, b15)
        CSTEP(4, 0, b16) CSTEP(4, 1, b17) CSTEP(4, 2, b18) CSTEP(4, 3, b19)
        CSTEP(5, 0, b20) CSTEP(5, 1, b21) CSTEP(5, 2, b22) CSTEP(5, 3, b23)
        CSTEP(6, 0, b24) CSTEP(6, 1, b25) CSTEP(6, 2, b26) CSTEP(6, 3, b27)
        CSTEP(7, 0, b28) CSTEP(7, 1, b29) CSTEP(7, 2, b30) CSTEP(7, 3, b31)
        CSTEP(8, 0, b32) CSTEP(8, 1, b33) CSTEP(8, 2, b34) CSTEP(8, 3, b35)

#pragma unroll
        for (int rr = 0; rr < 16; rr++) {
            s_acc  += acc[rr];
            ss_acc += acc[rr] * acc[rr];
        }
        if (m < OC) {
            const int ox0 = (w0 + t * TSX) >> 1;
            const size_t pbase = ((pb_n + m) * OH + oy) * OW;
#pragma unroll
            for (int rr = 0; rr < 16; rr++) {
                int p = (rr & 3) + 8 * (rr >> 2) + 4 * kg;
                if (p < 16 && (p & 1) == 0)
                    sigma_s[pbase + ox0 + (p >> 1)] = acc[rr];
            }
        }

        __syncthreads();
    }
#undef CSTEP

    s_acc  += __shfl_xor(s_acc, 32);
    ss_acc += __shfl_xor(ss_acc, 32);
    if (kg == 0 && m < OC) {
        atomicAdd(&sred[m], s_acc);
        atomicAdd(&sred[OC + m], ss_acc);
    }
    __syncthreads();
    if (tid < 2 * OC) part[tid * NWB + blockIdx.x] = sred[tid];
}

// ---------------------------------------------------------------------------
// Kernel C: BN finalize (hidden under sigma staging) + affine-in-softmax +
// 9-tap aggregation + coalesced output (r20 grid/decode preserved).
// ---------------------------------------------------------------------------
__global__ __launch_bounds__(256) void out_kernel(
        const uint4* __restrict__ xt, const float* __restrict__ sigma_s,
        const float* __restrict__ part,
        const float* __restrict__ gamma, const float* __restrict__ beta,
        float* __restrict__ out)
{
    __shared__ float p_lds[OC][64];     // 4.6 KB
    __shared__ float outs[64 * 65];     // 16.6 KB
    __shared__ float sred2[36 * 4];
    __shared__ float sscale[OC], sshift[OC];

    const int oh = blockIdx.x;
    const int n  = blockIdx.y >> 1;
    const int ow0 = (blockIdx.y & 1) * 64;
    const int h  = 2 * oh;
    const int tid = threadIdx.x;

    // ---- BN partial reduce (threads 0..143) — overlapped with sigma staging ----
    if (tid < 144) {
        int row = tid >> 2, q = tid & 3;
        const float4* p4 = (const float4*)(part + row * NWB) + q * 32;
        float s = 0.f;
#pragma unroll 8
        for (int k = 0; k < 32; k++) {
            float4 v = p4[k];
            s += (v.x + v.y) + (v.z + v.w);
        }
        sred2[row * 4 + q] = s;
    }

    // ---- sigma load RAW (all threads; independent of the reduction) ----
    for (int i = tid; i < OC * 64; i += 256) {
        int ch = i >> 6, owl = i & 63;
        p_lds[ch][owl] = sigma_s[((size_t)(n * OC + ch) * OH + oh) * OW + ow0 + owl];
    }
    __syncthreads();

    // ---- finalize scale/shift ----
    if (tid < OC) {
        float S = sred2[tid * 4] + sred2[tid * 4 + 1] + sred2[tid * 4 + 2] + sred2[tid * 4 + 3];
        float Q = sred2[(OC + tid) * 4] + sred2[(OC + tid) * 4 + 1] +
                  sred2[(OC + tid) * 4 + 2] + sred2[(OC + tid) * 4 + 3];
        float cf = (float)NB * H * W;
        float mean = S / cf;
        float var  = Q / cf - mean * mean;
        float sc   = gamma[tid] * rsqrtf(var + EPS);
        sscale[tid] = sc;
        sshift[tid] = beta[tid] - mean * sc;
    }
    __syncthreads();

    // ---- softmax per pixel, affine applied on read ----
    if (tid < 64) {
        int owl = tid;
        float v[OC];
        float mx = -1e30f;
#pragma unroll
        for (int ch = 0; ch < OC; ch++) {
            v[ch] = p_lds[ch][owl] * sscale[ch] + sshift[ch];
            mx = fmaxf(mx, v[ch]);
        }
        float e[OC], sum = 0.f;
#pragma unroll
        for (int ch = 0; ch < OC; ch++) { e[ch] = __expf(v[ch] - mx); sum += e[ch]; }
        float inv = 1.f / sum;
#pragma unroll
        for (int ch = 0; ch < OC; ch++) p_lds[ch][owl] = e[ch] * inv;
    }
    __syncthreads();

    int ihs[3];
#pragma unroll
    for (int kh = 0; kh < 3; kh++) ihs[kh] = refl(h - 1 + kh, H);

#pragma unroll
    for (int it = 0; it < 2; it++) {
        const int flat = it * 256 + tid;
        const int c8 = flat & 7;
        const int owl = flat >> 3;
        const int ow = ow0 + owl;
        const int g = (c8 >= 4) ? 1 : 0;

        float a[8];
#pragma unroll
        for (int j = 0; j < 8; j++) a[j] = 0.f;

#pragma unroll
        for (int kh = 0; kh < 3; kh++) {
            const size_t rb = ((size_t)(n * H + ihs[kh])) * W * 8;
#pragma unroll
            for (int kw = 0; kw < 3; kw++) {
                const int iw = refl(2 * ow - 1 + kw, W);
                const float p = p_lds[g * 9 + kh * 3 + kw][owl];
                uint4 v = xt[rb + (size_t)iw * 8 + c8];
                const unsigned uu[4] = {v.x, v.y, v.z, v.w};
#pragma unroll
                for (int q = 0; q < 4; q++) {
                    float lo = __builtin_bit_cast(float, uu[q] << 16);
                    float hi = __builtin_bit_cast(float, uu[q] & 0xffff0000u);
                    a[2 * q]     = fmaf(p, lo, a[2 * q]);
                    a[2 * q + 1] = fmaf(p, hi, a[2 * q + 1]);
                }
            }
        }

#pragma unroll
        for (int j = 0; j < 8; j++)
            outs[(c8 * 8 + j) * 65 + owl] = a[j];
    }
    __syncthreads();

    const size_t obase = ((size_t)n * CIN * OH + oh) * OW + ow0;
#pragma unroll
    for (int p2 = 0; p2 < 16; p2++) {
        int flat2 = p2 * 256 + tid;
        int c = flat2 >> 6, owl2 = flat2 & 63;
        out[obase + (size_t)c * OH * OW + owl2] = outs[c * 65 + owl2];
    }
}

// ---------------------------------------------------------------------------
extern "C" void kernel_launch(void* const* d_in, const int* in_sizes, int n_in,
                              void* d_out, int out_size, void* d_ws, size_t ws_size,
                              hipStream_t stream) {
    const float* x     = (const float*)d_in[0];
    const float* cw    = (const float*)d_in[1];
    const float* gamma = (const float*)d_in[2];
    const float* beta  = (const float*)d_in[3];
    float* out = (float*)d_out;
    float* ws  = (float*)d_ws;

    float* sigma_s = ws + 256;                              // 1,179,648 floats
    uint4* wBp     = (uint4*)(sigma_s + (size_t)NB * OC * OH * OW);   // 2304 uint4
    uint4* xtp     = wBp + 36 * 64;                         // 2,097,152 uint4
    float* part    = (float*)(xtp + (size_t)NB * H * W * 8);          // 36*512 floats

    dim3 gT(H, NB + 1);   // y==NB does the weight repack
    nhwc_kernel<<<gT, 256, 0, stream>>>(x, xtp, cw, wBp);

    conv_kernel<<<dim3(NWB), 256, 0, stream>>>(xtp, wBp, sigma_s, part);

    dim3 gC(OH, NB * 2);
    out_kernel<<<gC, 256, 0, stream>>>(xtp, sigma_s, part, gamma, beta, out);
}

// Round 23
// 50.311 us; speedup vs baseline: 1.1095x; 1.1095x over previous
//
#include <hip/hip_runtime.h>

typedef short bf16x8 __attribute__((ext_vector_type(8)));
typedef float f32x16 __attribute__((ext_vector_type(16)));

#define CIN 64
#define OC 18
#define NB 4
#define H 256
#define W 256
#define HW (H * W)
#define OH 128
#define OW 128
#define EPS 1e-5f

#define TSX 16          // conv tile cols
#define TSY 8           // conv tile rows
#define NTILE 4         // tiles per conv block
#define NWB 512         // number of conv blocks
#define ASLOTS 1536     // A halo: 1440 uint4 padded

__device__ __forceinline__ int refl(int i, int n) {
    if (i < 0) i = -i;
    if (i >= n) i = 2 * n - 2 - i;
    return i;
}

__device__ __forceinline__ unsigned pack_bf16(float a, float b) {
    __bf16 lo = (__bf16)a, hi = (__bf16)b;
    return (unsigned)__builtin_bit_cast(unsigned short, lo) |
           ((unsigned)__builtin_bit_cast(unsigned short, hi) << 16);
}

__device__ __forceinline__ void gload_lds16(const uint4* g, uint4* l) {
    __builtin_amdgcn_global_load_lds(
        (const __attribute__((address_space(1))) void*)(g),
        (__attribute__((address_space(3))) void*)(l), 16, 0, 0);
}

// ---------------------------------------------------------------------------
// NCHW fp32 -> NHWC bf16 transpose (+ fused weight repack on blockIdx.y==NB).
// ---------------------------------------------------------------------------
__global__ __launch_bounds__(256) void nhwc_kernel(
        const float* __restrict__ x, uint4* __restrict__ xt,
        const float* __restrict__ wgt, uint4* __restrict__ wB)
{
    if (blockIdx.y == NB) {
        if (blockIdx.x < 9) {
            int idx = blockIdx.x * 256 + threadIdx.x;   // s*64 + l
            int s = idx >> 6, l = idx & 63;
            int tap = s >> 2, ci0 = (s & 3) * 16;
            int oc = l & 31, kg = l >> 5;
            unsigned r[4];
#pragma unroll
            for (int jp = 0; jp < 4; jp++) {
                float v0 = 0.f, v1 = 0.f;
                int ci = ci0 + kg * 8 + jp * 2;
                if (oc < OC) {
                    v0 = wgt[(oc * CIN + ci) * 9 + tap];
                    v1 = wgt[(oc * CIN + ci + 1) * 9 + tap];
                }
                r[jp] = pack_bf16(v0, v1);
            }
            wB[idx] = make_uint4(r[0], r[1], r[2], r[3]);
        }
        return;
    }

    __shared__ uint4 bufq[2048];          // 32 KB
    unsigned* buf = (unsigned*)bufq;

    const int h = blockIdx.x, n = blockIdx.y;
    const int t = threadIdx.x;
    const int tpx = t & 63;
    const int cg = t >> 6;
    const int px0 = tpx * 4;
    const unsigned swz = ((unsigned)tpx & 7u) << 2;

    const float* xrow = x + ((size_t)n * CIN * H + h) * W;

#pragma unroll
    for (int ii = 0; ii < 4; ii++) {
        const int cq = cg * 4 + ii;
        const float4 A0 = *(const float4*)(xrow + (size_t)(4 * cq + 0) * HW + px0);
        const float4 A1 = *(const float4*)(xrow + (size_t)(4 * cq + 1) * HW + px0);
        const float4 A2 = *(const float4*)(xrow + (size_t)(4 * cq + 2) * HW + px0);
        const float4 A3 = *(const float4*)(xrow + (size_t)(4 * cq + 3) * HW + px0);
        const float a0[4] = {A0.x, A0.y, A0.z, A0.w};
        const float a1[4] = {A1.x, A1.y, A1.z, A1.w};
        const float a2[4] = {A2.x, A2.y, A2.z, A2.w};
        const float a3[4] = {A3.x, A3.y, A3.z, A3.w};
#pragma unroll
        for (int i = 0; i < 4; i++) {
            unsigned lo = pack_bf16(a0[i], a1[i]);
            unsigned hi = pack_bf16(a2[i], a3[i]);
            unsigned widx = (unsigned)(px0 + i) * 32u + ((unsigned)(2 * cq) ^ swz);
            *(uint2*)&buf[widx] = make_uint2(lo, hi);
        }
    }
    __syncthreads();

    const size_t rowbase = ((size_t)(n * H + h)) * W * 8;
#pragma unroll
    for (int i = 0; i < 8; i++) {
        int flat = i * 256 + t;
        int px = flat >> 3, j = flat & 7;
        unsigned sw = (((unsigned)px >> 2) & 7u) << 2;
        uint4 v = *(const uint4*)&buf[(unsigned)px * 32u + (((unsigned)(4 * j)) ^ sw)];
        xt[rowbase + flat] = v;
    }
}

// ---------------------------------------------------------------------------
// Kernel A: persistent-tile implicit-GEMM bf16 MFMA conv.
// A staged via ASYNC global_load_lds width-16 (linear LDS, source octet
// pre-swizzled c^=(px&7); reads XOR the same involution).
// B in 36 NAMED uint4 registers. ONE barrier per tile.
// BN partials to part[36][NWB].
// D (32x32): col = lane&31 = oc, row = (reg&3)+8*(reg>>2)+4*(lane>>5) = pixel.
// ---------------------------------------------------------------------------
__global__ __launch_bounds__(256, 2) void conv_kernel(
        const uint4* __restrict__ xt, const uint4* __restrict__ wB,
        float* __restrict__ sigma_s, float* __restrict__ part)
{
    __shared__ uint4 aldsq[2][ASLOTS];     // 2 x 24,576 B
    __shared__ float sred[2 * OC];

    const int tid = threadIdx.x;
    const int lane = tid & 63;

    const int b = blockIdx.x;
    const int cls = b & 7;
    const int L = b >> 3;
    const int n = cls >> 1;
    const int hhalf = cls & 1;
    const int ht = L >> 2;
    const int wq = L & 3;
    const int h0 = (hhalf * 16 + ht) * TSY;
    const int w0 = wq * (NTILE * TSX);

    if (tid < 2 * OC) sred[tid] = 0.f;

    int gbase[6], apx[6];
#pragma unroll
    for (int i = 0; i < 6; i++) {
        int e = tid + i * 256;
        int row = e / 144;
        int rem = e - row * 144;
        int px  = rem >> 3;
        int cs  = rem & 7;
        int csrc = cs ^ (px & 7);
        int gh  = refl(h0 + row - 1, H);
        gbase[i] = (n * H + gh) * W * 8 + csrc;
        apx[i]  = px;
    }

    // ---- issue A tile 0 (async) ----
#pragma unroll
    for (int i = 0; i < 6; i++) {
        int gw = refl(w0 + apx[i] - 1, W);
        gload_lds16(xt + (size_t)gbase[i] + (size_t)gw * 8,
                    &aldsq[0][tid + i * 256]);
    }

    // ---- B fragments -> 36 NAMED registers (wB already zero-padded) ----
    const uint4* wL = wB + lane;
    uint4 b00 = wL[ 0*64], b01 = wL[ 1*64], b02 = wL[ 2*64], b03 = wL[ 3*64];
    uint4 b04 = wL[ 4*64], b05 = wL[ 5*64], b06 = wL[ 6*64], b07 = wL[ 7*64];
    uint4 b08 = wL[ 8*64], b09 = wL[ 9*64], b10 = wL[10*64], b11 = wL[11*64];
    uint4 b12 = wL[12*64], b13 = wL[13*64], b14 = wL[14*64], b15 = wL[15*64];
    uint4 b16 = wL[16*64], b17 = wL[17*64], b18 = wL[18*64], b19 = wL[19*64];
    uint4 b20 = wL[20*64], b21 = wL[21*64], b22 = wL[22*64], b23 = wL[23*64];
    uint4 b24 = wL[24*64], b25 = wL[25*64], b26 = wL[26*64], b27 = wL[27*64];
    uint4 b28 = wL[28*64], b29 = wL[29*64], b30 = wL[30*64], b31 = wL[31*64];
    uint4 b32 = wL[32*64], b33 = wL[33*64], b34 = wL[34*64], b35 = wL[35*64];

    __syncthreads();

    const int wv = tid >> 6;
    const int m = lane & 31;
    const int kg = lane >> 5;
    const int pr = m >> 4, pc = m & 15;
    const int r0 = 2 * wv + pr;

    float s_acc = 0.f, ss_acc = 0.f;
    const int oy = (h0 >> 1) + wv;
    const size_t pb_n = (size_t)n * OC;

#define CSTEP(G, Q, BV)                                                        \
    {                                                                          \
        const int rp  = (r0 + (G / 3)) * 144 + (pc + (G % 3)) * 8;             \
        const int swk = (pc + (G % 3)) & 7;                                    \
        uint4 af = aq[rp + ((kg + 2 * (Q)) ^ swk)];                            \
        acc = __builtin_amdgcn_mfma_f32_32x32x16_bf16(                         \
                __builtin_bit_cast(bf16x8, af),                                \
                __builtin_bit_cast(bf16x8, BV), acc, 0, 0, 0);                 \
    }

#pragma unroll 1
    for (int t = 0; t < NTILE; t++) {
        if (t + 1 < NTILE) {
            const int w0n = w0 + (t + 1) * TSX;
            uint4* dst = &aldsq[(t + 1) & 1][0];
#pragma unroll
            for (int i = 0; i < 6; i++) {
                int gw = refl(w0n + apx[i] - 1, W);
                gload_lds16(xt + (size_t)gbase[i] + (size_t)gw * 8,
                            dst + tid + i * 256);
            }
        }

        const uint4* aq = &aldsq[t & 1][0];
        f32x16 acc = {};
        CSTEP(0, 0, b00) CSTEP(0, 1, b01) CSTEP(0, 2, b02) CSTEP(0, 3, b03)
        CSTEP(1, 0, b04) CSTEP(1, 1, b05) CSTEP(1, 2, b06) CSTEP(1, 3, b07)
        CSTEP(2, 0, b08) CSTEP(2, 1, b09) CSTEP(2, 2, b10) CSTEP(2, 3, b11)
        CSTEP(3, 0, b12) CSTEP(3, 1, b13) CSTEP(3, 2, b14) CSTEP(3, 3, b15)
        CSTEP(4, 0, b16) CSTEP(4, 1, b17) CSTEP(4, 2, b18) CSTEP(4, 3, b19)
        CSTEP(5, 0, b20) CSTEP(5, 1, b21) CSTEP(5, 2, b22) CSTEP(5, 3, b23)
        CSTEP(6, 0, b24) CSTEP(6, 1, b25) CSTEP(6, 2, b26) CSTEP(6, 3, b27)
        CSTEP(7, 0, b28) CSTEP(7, 1, b29) CSTEP(7, 2, b30) CSTEP(7, 3, b31)
        CSTEP(8, 0, b32) CSTEP(8, 1, b33) CSTEP(8, 2, b34) CSTEP(8, 3, b35)

#pragma unroll
        for (int rr = 0; rr < 16; rr++) {
            s_acc  += acc[rr];
            ss_acc += acc[rr] * acc[rr];
        }
        if (m < OC) {
            const int ox0 = (w0 + t * TSX) >> 1;
            const size_t pbase = ((pb_n + m) * OH + oy) * OW;
#pragma unroll
            for (int rr = 0; rr < 16; rr++) {
                int p = (rr & 3) + 8 * (rr >> 2) + 4 * kg;
                if (p < 16 && (p & 1) == 0)
                    sigma_s[pbase + ox0 + (p >> 1)] = acc[rr];
            }
        }

        __syncthreads();
    }
#undef CSTEP

    s_acc  += __shfl_xor(s_acc, 32);
    ss_acc += __shfl_xor(ss_acc, 32);
    if (kg == 0 && m < OC) {
        atomicAdd(&sred[m], s_acc);
        atomicAdd(&sred[OC + m], ss_acc);
    }
    __syncthreads();
    if (tid < 2 * OC) part[tid * NWB + blockIdx.x] = sred[tid];
}

// ---------------------------------------------------------------------------
// Kernel B: reduce per-block partials + finalize BN -> scale/shift.
// ---------------------------------------------------------------------------
__global__ __launch_bounds__(256) void bn_kernel(
        const float* __restrict__ gamma, const float* __restrict__ beta,
        const float* __restrict__ part, float* __restrict__ stats)
{
    __shared__ float red[8];
    const int c = blockIdx.x;
    const int tid = threadIdx.x;

    float s  = part[c * NWB + tid]        + part[c * NWB + 256 + tid];
    float ss = part[(OC + c) * NWB + tid] + part[(OC + c) * NWB + 256 + tid];
#pragma unroll
    for (int off = 32; off > 0; off >>= 1) {
        s  += __shfl_down(s, off);
        ss += __shfl_down(ss, off);
    }
    const int wid = tid >> 6, lanez = tid & 63;
    if (lanez == 0) { red[wid] = s; red[4 + wid] = ss; }
    __syncthreads();
    if (tid == 0) {
        float S  = red[0] + red[1] + red[2] + red[3];
        float SS = red[4] + red[5] + red[6] + red[7];
        float cnt = (float)NB * H * W;
        float mean = S / cnt;
        float var  = SS / cnt - mean * mean;
        float sc   = gamma[c] * rsqrtf(var + EPS);
        stats[36 + c] = sc;
        stats[54 + c] = beta[c] - mean * sc;
    }
}

// ---------------------------------------------------------------------------
// Kernel C: BN-affine + softmax(18) + 9-tap aggregation from NHWC bf16
// + coalesced output via LDS staging.
// ---------------------------------------------------------------------------
__global__ __launch_bounds__(256) void out_kernel(
        const uint4* __restrict__ xt, const float* __restrict__ sigma_s,
        const float* __restrict__ stats, float* __restrict__ out)
{
    __shared__ float p_lds[OC][64];     // 4.6 KB
    __shared__ float outs[64 * 65];     // 16.6 KB

    const int oh = blockIdx.x;
    const int n  = blockIdx.y >> 1;
    const int ow0 = (blockIdx.y & 1) * 64;
    const int h  = 2 * oh;
    const int tid = threadIdx.x;

    for (int i = tid; i < OC * 64; i += 256) {
        int ch = i >> 6, owl = i & 63;
        float v = sigma_s[((size_t)(n * OC + ch) * OH + oh) * OW + ow0 + owl];
        p_lds[ch][owl] = v * stats[36 + ch] + stats[54 + ch];
    }
    __syncthreads();

    if (tid < 64) {
        int owl = tid;
        float mx = -1e30f;
#pragma unroll
        for (int ch = 0; ch < OC; ch++) mx = fmaxf(mx, p_lds[ch][owl]);
        float e[OC], sum = 0.f;
#pragma unroll
        for (int ch = 0; ch < OC; ch++) { e[ch] = __expf(p_lds[ch][owl] - mx); sum += e[ch]; }
        float inv = 1.f / sum;
#pragma unroll
        for (int ch = 0; ch < OC; ch++) p_lds[ch][owl] = e[ch] * inv;
    }
    __syncthreads();

    int ihs[3];
#pragma unroll
    for (int kh = 0; kh < 3; kh++) ihs[kh] = refl(h - 1 + kh, H);

#pragma unroll
    for (int it = 0; it < 2; it++) {
        const int flat = it * 256 + tid;
        const int c8 = flat & 7;
        const int owl = flat >> 3;
        const int ow = ow0 + owl;
        const int g = (c8 >= 4) ? 1 : 0;

        float a[8];
#pragma unroll
        for (int j = 0; j < 8; j++) a[j] = 0.f;

#pragma unroll
        for (int kh = 0; kh < 3; kh++) {
            const size_t rb = ((size_t)(n * H + ihs[kh])) * W * 8;
#pragma unroll
            for (int kw = 0; kw < 3; kw++) {
                const int iw = refl(2 * ow - 1 + kw, W);
                const float p = p_lds[g * 9 + kh * 3 + kw][owl];
                uint4 v = xt[rb + (size_t)iw * 8 + c8];
                const unsigned uu[4] = {v.x, v.y, v.z, v.w};
#pragma unroll
                for (int q = 0; q < 4; q++) {
                    float lo = __builtin_bit_cast(float, uu[q] << 16);
                    float hi = __builtin_bit_cast(float, uu[q] & 0xffff0000u);
                    a[2 * q]     = fmaf(p, lo, a[2 * q]);
                    a[2 * q + 1] = fmaf(p, hi, a[2 * q + 1]);
                }
            }
        }

#pragma unroll
        for (int j = 0; j < 8; j++)
            outs[(c8 * 8 + j) * 65 + owl] = a[j];
    }
    __syncthreads();

    const size_t obase = ((size_t)n * CIN * OH + oh) * OW + ow0;
#pragma unroll
    for (int p2 = 0; p2 < 16; p2++) {
        int flat2 = p2 * 256 + tid;
        int c = flat2 >> 6, owl2 = flat2 & 63;
        out[obase + (size_t)c * OH * OW + owl2] = outs[c * 65 + owl2];
    }
}

// ---------------------------------------------------------------------------
extern "C" void kernel_launch(void* const* d_in, const int* in_sizes, int n_in,
                              void* d_out, int out_size, void* d_ws, size_t ws_size,
                              hipStream_t stream) {
    const float* x     = (const float*)d_in[0];
    const float* cw    = (const float*)d_in[1];
    const float* gamma = (const float*)d_in[2];
    const float* beta  = (const float*)d_in[3];
    float* out = (float*)d_out;
    float* ws  = (float*)d_ws;

    float* stats   = ws;                                    // 256 floats
    float* sigma_s = ws + 256;                              // 1,179,648 floats
    uint4* wBp     = (uint4*)(sigma_s + (size_t)NB * OC * OH * OW);   // 2304 uint4
    uint4* xtp     = wBp + 36 * 64;                         // 2,097,152 uint4
    float* part    = (float*)(xtp + (size_t)NB * H * W * 8);          // 36*512 floats

    dim3 gT(H, NB + 1);   // y==NB does the weight repack
    nhwc_kernel<<<gT, 256, 0, stream>>>(x, xtp, cw, wBp);

    conv_kernel<<<dim3(NWB), 256, 0, stream>>>(xtp, wBp, sigma_s, part);

    bn_kernel<<<OC, 256, 0, stream>>>(gamma, beta, part, stats);

    dim3 gC(OH, NB * 2);
    out_kernel<<<gC, 256, 0, stream>>>(xtp, sigma_s, stats, out);
}